// Round 1
// baseline (549.438 us; speedup 1.0000x reference)
//
#include <hip/hip_runtime.h>
#include <hip/hip_bf16.h>

#define LOG2E 1.44269504088896340736f

typedef __attribute__((ext_vector_type(8))) short short8;
typedef __attribute__((ext_vector_type(4))) float f32x4;

__device__ __forceinline__ unsigned short f2bf(float f) {
    unsigned int u = __float_as_uint(f);
    u += 0x7fffu + ((u >> 16) & 1u);
    return (unsigned short)(u >> 16);
}

// ---------------- fp32 -> bf16 conversion ----------------
__global__ void cvt_f32_to_bf16(const float* __restrict__ in,
                                unsigned short* __restrict__ out, int n4) {
    int stride = gridDim.x * blockDim.x;
    for (int i = blockIdx.x * blockDim.x + threadIdx.x; i < n4; i += stride) {
        float4 v = ((const float4*)in)[i];
        ushort4 o;
        o.x = f2bf(v.x); o.y = f2bf(v.y); o.z = f2bf(v.z); o.w = f2bf(v.w);
        ((ushort4*)out)[i] = o;
    }
}

// ---------------- GEMM: C[m][n] = sum_k A[m][k]*B[n][k] (+bias) ----------------
// A: M x K bf16 row-major; B: N x K bf16 row-major (i.e. "B^T" form).
// 128x128 tile, 4 waves (2x2), each wave 64x64. BK=64.
// EPI==0: scatter to qkv_sep (3,B,nh,N,hd) bf16.  EPI==1: fp32 out (M x N).
template <int EPI>
__global__ __launch_bounds__(256, 2)
void gemm_bt(const unsigned short* __restrict__ A,
             const unsigned short* __restrict__ B,
             const float* __restrict__ bias,
             void* __restrict__ Cout,
             int M, int N, int K) {
    __shared__ unsigned short As[128][72];
    __shared__ unsigned short Bs[128][72];

    const int tid  = threadIdx.x;
    const int wave = tid >> 6, lane = tid & 63;
    const int fr = lane & 15, fg = lane >> 4;
    const int wm = (wave >> 1) * 64, wn = (wave & 1) * 64;
    const int m0 = blockIdx.y * 128, n0 = blockIdx.x * 128;
    const int trow = tid >> 3, tseg = tid & 7;

    f32x4 acc[4][4];
#pragma unroll
    for (int m = 0; m < 4; m++)
#pragma unroll
        for (int n = 0; n < 4; n++) acc[m][n] = (f32x4){0.f, 0.f, 0.f, 0.f};

    for (int k0 = 0; k0 < K; k0 += 64) {
        __syncthreads();
#pragma unroll
        for (int c = 0; c < 4; c++) {
            int r = trow + c * 32;
            *(short8*)&As[r][tseg * 8] =
                *(const short8*)(A + (size_t)(m0 + r) * K + k0 + tseg * 8);
            *(short8*)&Bs[r][tseg * 8] =
                *(const short8*)(B + (size_t)(n0 + r) * K + k0 + tseg * 8);
        }
        __syncthreads();
#pragma unroll
        for (int ks = 0; ks < 2; ks++) {
            short8 af[4], bfr[4];
#pragma unroll
            for (int m = 0; m < 4; m++)
                af[m] = *(const short8*)&As[wm + m * 16 + fr][ks * 32 + fg * 8];
#pragma unroll
            for (int n = 0; n < 4; n++)
                bfr[n] = *(const short8*)&Bs[wn + n * 16 + fr][ks * 32 + fg * 8];
#pragma unroll
            for (int m = 0; m < 4; m++)
#pragma unroll
                for (int n = 0; n < 4; n++)
                    acc[m][n] = __builtin_amdgcn_mfma_f32_16x16x32_bf16(
                        af[m], bfr[n], acc[m][n], 0, 0, 0);
        }
    }

#pragma unroll
    for (int m = 0; m < 4; m++) {
#pragma unroll
        for (int n = 0; n < 4; n++) {
            int gn = n0 + wn + n * 16 + fr;
            float bv = bias[gn];
#pragma unroll
            for (int j = 0; j < 4; j++) {
                int gm = m0 + wm + m * 16 + fg * 4 + j;
                float v = acc[m][n][j] + bv;
                if (EPI == 0) {
                    // gn in [0,2304): which = q/k/v, then head, then dim
                    int which = gn / 768, rem = gn % 768;
                    int h = rem >> 6, d = rem & 63;
                    int b = gm >> 12, nn = gm & 4095;
                    unsigned short* o = (unsigned short*)Cout;
                    o[((((size_t)which * 2 + b) * 12 + h) * 4096 + nn) * 64 + d] = f2bf(v);
                } else {
                    float* o = (float*)Cout;
                    o[(size_t)gm * 768 + gn] = v;
                }
            }
        }
    }
}

// ---------------- Flash attention ----------------
// qkv: (3, B, nh, N, hd) bf16.  out: (B, N, nh*hd) bf16.
// Block: 256 threads = 4 waves; Q tile = 128 rows (32/wave, in registers);
// KV tiles of 64 staged in LDS (K row-major padded; V transposed -> Vt[d][k]).
__global__ __launch_bounds__(256, 2)
void attn_fwd(const unsigned short* __restrict__ qkv,
              unsigned short* __restrict__ outp) {
    __shared__ unsigned short Ks[64][72];
    __shared__ unsigned short Vt[64][72];        // Vt[d][k]
    __shared__ unsigned short Ps[4][32][72];     // per-wave P tile

    const int tid  = threadIdx.x;
    const int wave = tid >> 6, lane = tid & 63;
    const int fr = lane & 15, fg = lane >> 4;

    const int qt = blockIdx.x;        // q tile 0..31
    const int bh = blockIdx.y;        // 0..23
    const int b = bh / 12, h = bh % 12;

    const size_t headsz = (size_t)4096 * 64;
    const unsigned short* qh = qkv + ((size_t)(0 * 2 + b) * 12 + h) * headsz;
    const unsigned short* kh = qkv + ((size_t)(1 * 2 + b) * 12 + h) * headsz;
    const unsigned short* vh = qkv + ((size_t)(2 * 2 + b) * 12 + h) * headsz;

    const int qw = qt * 128 + wave * 32;

    // Q fragments in registers: [m-frag][k-step]
    short8 qf[2][2];
#pragma unroll
    for (int m = 0; m < 2; m++)
#pragma unroll
        for (int ks = 0; ks < 2; ks++)
            qf[m][ks] = *(const short8*)(qh + (size_t)(qw + m * 16 + fr) * 64 +
                                         ks * 32 + fg * 8);

    float mrow[2][4], lrow[2][4];
    f32x4 accO[2][4];
#pragma unroll
    for (int m = 0; m < 2; m++) {
#pragma unroll
        for (int j = 0; j < 4; j++) { mrow[m][j] = -1e30f; lrow[m][j] = 0.f; }
#pragma unroll
        for (int n = 0; n < 4; n++) accO[m][n] = (f32x4){0.f, 0.f, 0.f, 0.f};
    }

    const int r = tid >> 3, sg = tid & 7;

    for (int kt = 0; kt < 64; kt++) {
        __syncthreads();
        const unsigned short* kb = kh + (size_t)kt * 64 * 64;
        const unsigned short* vb = vh + (size_t)kt * 64 * 64;
#pragma unroll
        for (int c = 0; c < 2; c++) {
            int kr = r + c * 32;
            *(short8*)&Ks[kr][sg * 8] = *(const short8*)(kb + kr * 64 + sg * 8);
            short8 vv = *(const short8*)(vb + kr * 64 + sg * 8);
#pragma unroll
            for (int t = 0; t < 8; t++)
                Vt[sg * 8 + t][kr] = (unsigned short)vv[t];
        }
        __syncthreads();

        // S = (Q*scale) K^T  (scale applied post-MFMA)
        f32x4 s[2][4];
#pragma unroll
        for (int m = 0; m < 2; m++)
#pragma unroll
            for (int n = 0; n < 4; n++) s[m][n] = (f32x4){0.f, 0.f, 0.f, 0.f};
#pragma unroll
        for (int ks = 0; ks < 2; ks++) {
            short8 kf[4];
#pragma unroll
            for (int n = 0; n < 4; n++)
                kf[n] = *(const short8*)&Ks[n * 16 + fr][ks * 32 + fg * 8];
#pragma unroll
            for (int m = 0; m < 2; m++)
#pragma unroll
                for (int n = 0; n < 4; n++)
                    s[m][n] = __builtin_amdgcn_mfma_f32_16x16x32_bf16(
                        qf[m][ks], kf[n], s[m][n], 0, 0, 0);
        }
#pragma unroll
        for (int m = 0; m < 2; m++)
#pragma unroll
            for (int n = 0; n < 4; n++) s[m][n] *= 0.125f;

        // online softmax: rows live on (fg, j); cols across fr lanes
#pragma unroll
        for (int m = 0; m < 2; m++) {
#pragma unroll
            for (int j = 0; j < 4; j++) {
                float mx = fmaxf(fmaxf(s[m][0][j], s[m][1][j]),
                                 fmaxf(s[m][2][j], s[m][3][j]));
#pragma unroll
                for (int off = 1; off < 16; off <<= 1)
                    mx = fmaxf(mx, __shfl_xor(mx, off));
                float mnew = fmaxf(mrow[m][j], mx);
                float corr = exp2f((mrow[m][j] - mnew) * LOG2E);
                mrow[m][j] = mnew;
                float rsum = 0.f;
#pragma unroll
                for (int n = 0; n < 4; n++) {
                    float p = exp2f((s[m][n][j] - mnew) * LOG2E);
                    s[m][n][j] = p;
                    rsum += p;
                }
#pragma unroll
                for (int off = 1; off < 16; off <<= 1)
                    rsum += __shfl_xor(rsum, off);
                lrow[m][j] = lrow[m][j] * corr + rsum;
#pragma unroll
                for (int n = 0; n < 4; n++) accO[m][n][j] *= corr;
            }
        }

        // P -> LDS (bf16) for re-fragmenting (same-wave RAW, compiler-ordered)
#pragma unroll
        for (int m = 0; m < 2; m++)
#pragma unroll
            for (int n = 0; n < 4; n++)
#pragma unroll
                for (int j = 0; j < 4; j++)
                    Ps[wave][m * 16 + fg * 4 + j][n * 16 + fr] = f2bf(s[m][n][j]);

        // O += P V   (A = P rows; B = V[k][d] read from Vt[d][k])
#pragma unroll
        for (int ks = 0; ks < 2; ks++) {
            short8 pf[2], vf[4];
#pragma unroll
            for (int m = 0; m < 2; m++)
                pf[m] = *(const short8*)&Ps[wave][m * 16 + fr][ks * 32 + fg * 8];
#pragma unroll
            for (int n = 0; n < 4; n++)
                vf[n] = *(const short8*)&Vt[n * 16 + fr][ks * 32 + fg * 8];
#pragma unroll
            for (int m = 0; m < 2; m++)
#pragma unroll
                for (int n = 0; n < 4; n++)
                    accO[m][n] = __builtin_amdgcn_mfma_f32_16x16x32_bf16(
                        pf[m], vf[n], accO[m][n], 0, 0, 0);
        }
    }

    // epilogue: O / l -> out (B, N, 768) bf16
#pragma unroll
    for (int m = 0; m < 2; m++) {
#pragma unroll
        for (int j = 0; j < 4; j++) {
            float inv = 1.0f / lrow[m][j];
            int gq = qw + m * 16 + fg * 4 + j;
#pragma unroll
            for (int n = 0; n < 4; n++) {
                int gd = n * 16 + fr;
                outp[(size_t)(b * 4096 + gq) * 768 + h * 64 + gd] =
                    f2bf(accO[m][n][j] * inv);
            }
        }
    }
}

// ---------------- launch ----------------
extern "C" void kernel_launch(void* const* d_in, const int* in_sizes, int n_in,
                              void* d_out, int out_size, void* d_ws, size_t ws_size,
                              hipStream_t stream) {
    const float* x      = (const float*)d_in[0];
    const float* qkv_w  = (const float*)d_in[1];
    const float* qkv_b  = (const float*)d_in[2];
    const float* proj_w = (const float*)d_in[3];
    const float* proj_b = (const float*)d_in[4];
    float* out = (float*)d_out;

    char* ws = (char*)d_ws;
    unsigned short* x_bf    = (unsigned short*)(ws);              // 12,582,912 B
    unsigned short* w1_bf   = (unsigned short*)(ws + 12582912);   //  3,538,944 B
    unsigned short* w2_bf   = (unsigned short*)(ws + 16121856);   //  1,179,648 B
    unsigned short* qkv_sep = (unsigned short*)(ws + 17301504);   // 37,748,736 B
    unsigned short* att     = (unsigned short*)(ws + 55050240);   // 12,582,912 B (end 67,633,152)

    // fp32 -> bf16 conversions
    cvt_f32_to_bf16<<<2048, 256, 0, stream>>>(x,      x_bf,  6291456 / 4);
    cvt_f32_to_bf16<<<1024, 256, 0, stream>>>(qkv_w,  w1_bf, 1769472 / 4);
    cvt_f32_to_bf16<<<576,  256, 0, stream>>>(proj_w, w2_bf,  589824 / 4);

    // QKV projection: (8192 x 768) x (2304 x 768)^T -> scatter (3,B,nh,N,hd)
    gemm_bt<0><<<dim3(18, 64), 256, 0, stream>>>(x_bf, w1_bf, qkv_b, qkv_sep,
                                                 8192, 2304, 768);

    // flash attention -> att (B, N, 768) bf16
    attn_fwd<<<dim3(32, 24), 256, 0, stream>>>(qkv_sep, att);

    // output projection: (8192 x 768) x (768 x 768)^T -> fp32 out
    gemm_bt<1><<<dim3(6, 64), 256, 0, stream>>>(att, w2_bf, proj_b, out,
                                                8192, 768, 768);
}

// Round 2
// 529.036 us; speedup vs baseline: 1.0386x; 1.0386x over previous
//
#include <hip/hip_runtime.h>
#include <hip/hip_bf16.h>

#define LOG2E 1.44269504088896340736f

typedef __attribute__((ext_vector_type(8))) short short8;
typedef __attribute__((ext_vector_type(4))) float f32x4;

__device__ __forceinline__ unsigned short f2bf(float f) {
    unsigned int u = __float_as_uint(f);
    u += 0x7fffu + ((u >> 16) & 1u);
    return (unsigned short)(u >> 16);
}

// ---------------- fp32 -> bf16 conversion ----------------
__global__ void cvt_f32_to_bf16(const float* __restrict__ in,
                                unsigned short* __restrict__ out, int n4) {
    int stride = gridDim.x * blockDim.x;
    for (int i = blockIdx.x * blockDim.x + threadIdx.x; i < n4; i += stride) {
        float4 v = ((const float4*)in)[i];
        ushort4 o;
        o.x = f2bf(v.x); o.y = f2bf(v.y); o.z = f2bf(v.z); o.w = f2bf(v.w);
        ((ushort4*)out)[i] = o;
    }
}

// ---------------- GEMM: C[m][n] = sum_k A[m][k]*B[n][k] (+bias) ----------------
// A: M x K bf16 row-major; B: N x K bf16 row-major (i.e. "B^T" form).
// 128x128 tile, 4 waves (2x2), each wave 64x64. BK=64.
// EPI==0: scatter to qkv_sep; q,k stored (B,nh,N,hd); V stored (B,nh,hd,N) TRANSPOSED.
// EPI==1: fp32 out (M x N).
template <int EPI>
__global__ __launch_bounds__(256, 2)
void gemm_bt(const unsigned short* __restrict__ A,
             const unsigned short* __restrict__ B,
             const float* __restrict__ bias,
             void* __restrict__ Cout,
             int M, int N, int K) {
    __shared__ unsigned short As[128][72];
    __shared__ unsigned short Bs[128][72];

    const int tid  = threadIdx.x;
    const int wave = tid >> 6, lane = tid & 63;
    const int fr = lane & 15, fg = lane >> 4;
    const int wm = (wave >> 1) * 64, wn = (wave & 1) * 64;
    const int m0 = blockIdx.y * 128, n0 = blockIdx.x * 128;
    const int trow = tid >> 3, tseg = tid & 7;

    f32x4 acc[4][4];
#pragma unroll
    for (int m = 0; m < 4; m++)
#pragma unroll
        for (int n = 0; n < 4; n++) acc[m][n] = (f32x4){0.f, 0.f, 0.f, 0.f};

    for (int k0 = 0; k0 < K; k0 += 64) {
        __syncthreads();
#pragma unroll
        for (int c = 0; c < 4; c++) {
            int r = trow + c * 32;
            *(short8*)&As[r][tseg * 8] =
                *(const short8*)(A + (size_t)(m0 + r) * K + k0 + tseg * 8);
            *(short8*)&Bs[r][tseg * 8] =
                *(const short8*)(B + (size_t)(n0 + r) * K + k0 + tseg * 8);
        }
        __syncthreads();
#pragma unroll
        for (int ks = 0; ks < 2; ks++) {
            short8 af[4], bfr[4];
#pragma unroll
            for (int m = 0; m < 4; m++)
                af[m] = *(const short8*)&As[wm + m * 16 + fr][ks * 32 + fg * 8];
#pragma unroll
            for (int n = 0; n < 4; n++)
                bfr[n] = *(const short8*)&Bs[wn + n * 16 + fr][ks * 32 + fg * 8];
#pragma unroll
            for (int m = 0; m < 4; m++)
#pragma unroll
                for (int n = 0; n < 4; n++)
                    acc[m][n] = __builtin_amdgcn_mfma_f32_16x16x32_bf16(
                        af[m], bfr[n], acc[m][n], 0, 0, 0);
        }
    }

#pragma unroll
    for (int m = 0; m < 4; m++) {
#pragma unroll
        for (int n = 0; n < 4; n++) {
            int gn = n0 + wn + n * 16 + fr;
            float bv = bias[gn];
#pragma unroll
            for (int j = 0; j < 4; j++) {
                int gm = m0 + wm + m * 16 + fg * 4 + j;
                float v = acc[m][n][j] + bv;
                if (EPI == 0) {
                    // gn in [0,2304): which = q/k/v, then head, then dim
                    int which = gn / 768, rem = gn % 768;
                    int h = rem >> 6, d = rem & 63;
                    int b = gm >> 12, nn = gm & 4095;
                    unsigned short* o = (unsigned short*)Cout;
                    size_t base = (((size_t)which * 2 + b) * 12 + h) * 262144;
                    if (which == 2)
                        o[base + (size_t)d * 4096 + nn] = f2bf(v);   // V^T: (hd, N)
                    else
                        o[base + (size_t)nn * 64 + d] = f2bf(v);     // Q,K: (N, hd)
                } else {
                    float* o = (float*)Cout;
                    o[(size_t)gm * 768 + gn] = v;
                }
            }
        }
    }
}

// ---------------- Flash attention ----------------
// qkv: q,k as (B,nh,N,hd); v as (B,nh,hd,N) bf16.  out: (B, N, nh*hd) bf16.
// Block: 256 threads = 4 waves; Q tile = 128 rows (32/wave, in registers);
// KV tiles of 64 staged in LDS (K row-major padded; Vt loaded directly from V^T).
__global__ __launch_bounds__(256, 2)
void attn_fwd(const unsigned short* __restrict__ qkv,
              unsigned short* __restrict__ outp) {
    __shared__ unsigned short Ks[64][72];
    __shared__ unsigned short Vt[64][72];        // Vt[d][k]
    __shared__ unsigned short Ps[4][32][72];     // per-wave P tile, col-swizzled

    const int tid  = threadIdx.x;
    const int wave = tid >> 6, lane = tid & 63;
    const int fr = lane & 15, fg = lane >> 4;

    const int qt = blockIdx.x;        // q tile 0..31
    const int bh = blockIdx.y;        // 0..23
    const int b = bh / 12, h = bh % 12;

    const size_t headsz = (size_t)4096 * 64;
    const unsigned short* qh  = qkv + ((size_t)(0 * 2 + b) * 12 + h) * headsz;
    const unsigned short* kh  = qkv + ((size_t)(1 * 2 + b) * 12 + h) * headsz;
    const unsigned short* vht = qkv + ((size_t)(2 * 2 + b) * 12 + h) * headsz; // (hd,N)

    const int qw = qt * 128 + wave * 32;

    // Q fragments in registers: [m-frag][k-step]
    short8 qf[2][2];
#pragma unroll
    for (int m = 0; m < 2; m++)
#pragma unroll
        for (int ks = 0; ks < 2; ks++)
            qf[m][ks] = *(const short8*)(qh + (size_t)(qw + m * 16 + fr) * 64 +
                                         ks * 32 + fg * 8);

    float mrow[2][4], lrow[2][4];
    f32x4 accO[2][4];
#pragma unroll
    for (int m = 0; m < 2; m++) {
#pragma unroll
        for (int j = 0; j < 4; j++) { mrow[m][j] = -1e30f; lrow[m][j] = 0.f; }
#pragma unroll
        for (int n = 0; n < 4; n++) accO[m][n] = (f32x4){0.f, 0.f, 0.f, 0.f};
    }

    const int r = tid >> 3, sg = tid & 7;
    const float SCL = 0.125f * LOG2E;   // hd^-0.5 folded into exp2 domain

    for (int kt = 0; kt < 64; kt++) {
        __syncthreads();
        const unsigned short* kb = kh + (size_t)kt * 64 * 64;
#pragma unroll
        for (int c = 0; c < 2; c++) {
            int kr = r + c * 32;
            *(short8*)&Ks[kr][sg * 8] = *(const short8*)(kb + kr * 64 + sg * 8);
            // V^T rows: Vt[d][k] <- vht[d*4096 + kt*64 + k]
            *(short8*)&Vt[kr][sg * 8] =
                *(const short8*)(vht + (size_t)kr * 4096 + kt * 64 + sg * 8);
        }
        __syncthreads();

        // S = Q K^T (scale folded into exp2 domain below)
        f32x4 s[2][4];
#pragma unroll
        for (int m = 0; m < 2; m++)
#pragma unroll
            for (int n = 0; n < 4; n++) s[m][n] = (f32x4){0.f, 0.f, 0.f, 0.f};
#pragma unroll
        for (int ks = 0; ks < 2; ks++) {
            short8 kf[4];
#pragma unroll
            for (int n = 0; n < 4; n++)
                kf[n] = *(const short8*)&Ks[n * 16 + fr][ks * 32 + fg * 8];
#pragma unroll
            for (int m = 0; m < 2; m++)
#pragma unroll
                for (int n = 0; n < 4; n++)
                    s[m][n] = __builtin_amdgcn_mfma_f32_16x16x32_bf16(
                        qf[m][ks], kf[n], s[m][n], 0, 0, 0);
        }
        // move to exp2 domain: s2 = s * (scale*log2e)
#pragma unroll
        for (int m = 0; m < 2; m++)
#pragma unroll
            for (int n = 0; n < 4; n++) s[m][n] *= SCL;

        // online softmax (exp2 domain): rows live on (fg, j); cols across fr lanes
#pragma unroll
        for (int m = 0; m < 2; m++) {
#pragma unroll
            for (int j = 0; j < 4; j++) {
                float mx = fmaxf(fmaxf(s[m][0][j], s[m][1][j]),
                                 fmaxf(s[m][2][j], s[m][3][j]));
#pragma unroll
                for (int off = 1; off < 16; off <<= 1)
                    mx = fmaxf(mx, __shfl_xor(mx, off));
                float mnew = fmaxf(mrow[m][j], mx);
                float corr = exp2f(mrow[m][j] - mnew);
                mrow[m][j] = mnew;
                float rsum = 0.f;
#pragma unroll
                for (int n = 0; n < 4; n++) {
                    float p = exp2f(s[m][n][j] - mnew);
                    s[m][n][j] = p;
                    rsum += p;
                }
#pragma unroll
                for (int off = 1; off < 16; off <<= 1)
                    rsum += __shfl_xor(rsum, off);
                lrow[m][j] = lrow[m][j] * corr + rsum;
#pragma unroll
                for (int n = 0; n < 4; n++) accO[m][n][j] *= corr;
            }
        }

        // P -> LDS (bf16), col-swizzled: col' = col ^ (((row>>2)&3)<<3)
#pragma unroll
        for (int m = 0; m < 2; m++)
#pragma unroll
            for (int n = 0; n < 4; n++)
#pragma unroll
                for (int j = 0; j < 4; j++) {
                    int rw = m * 16 + fg * 4 + j;
                    int cs = (n * 16 + fr) ^ (((rw >> 2) & 3) << 3);
                    Ps[wave][rw][cs] = f2bf(s[m][n][j]);
                }

        // O += P V   (A = P rows; B = V[k][d] read from Vt[d][k])
#pragma unroll
        for (int ks = 0; ks < 2; ks++) {
            short8 pf[2], vf[4];
#pragma unroll
            for (int m = 0; m < 2; m++) {
                int rw = m * 16 + fr;
                int cs = (ks * 32 + fg * 8) ^ (((rw >> 2) & 3) << 3);
                pf[m] = *(const short8*)&Ps[wave][rw][cs];
            }
#pragma unroll
            for (int n = 0; n < 4; n++)
                vf[n] = *(const short8*)&Vt[n * 16 + fr][ks * 32 + fg * 8];
#pragma unroll
            for (int m = 0; m < 2; m++)
#pragma unroll
                for (int n = 0; n < 4; n++)
                    accO[m][n] = __builtin_amdgcn_mfma_f32_16x16x32_bf16(
                        pf[m], vf[n], accO[m][n], 0, 0, 0);
        }
    }

    // epilogue: O / l -> out (B, N, 768) bf16
#pragma unroll
    for (int m = 0; m < 2; m++) {
#pragma unroll
        for (int j = 0; j < 4; j++) {
            float inv = 1.0f / lrow[m][j];
            int gq = qw + m * 16 + fg * 4 + j;
#pragma unroll
            for (int n = 0; n < 4; n++) {
                int gd = n * 16 + fr;
                outp[(size_t)(b * 4096 + gq) * 768 + h * 64 + gd] =
                    f2bf(accO[m][n][j] * inv);
            }
        }
    }
}

// ---------------- launch ----------------
extern "C" void kernel_launch(void* const* d_in, const int* in_sizes, int n_in,
                              void* d_out, int out_size, void* d_ws, size_t ws_size,
                              hipStream_t stream) {
    const float* x      = (const float*)d_in[0];
    const float* qkv_w  = (const float*)d_in[1];
    const float* qkv_b  = (const float*)d_in[2];
    const float* proj_w = (const float*)d_in[3];
    const float* proj_b = (const float*)d_in[4];
    float* out = (float*)d_out;

    char* ws = (char*)d_ws;
    unsigned short* x_bf    = (unsigned short*)(ws);              // 12,582,912 B
    unsigned short* w1_bf   = (unsigned short*)(ws + 12582912);   //  3,538,944 B
    unsigned short* w2_bf   = (unsigned short*)(ws + 16121856);   //  1,179,648 B
    unsigned short* qkv_sep = (unsigned short*)(ws + 17301504);   // 37,748,736 B
    unsigned short* att     = (unsigned short*)(ws + 55050240);   // 12,582,912 B (end 67,633,152)

    // fp32 -> bf16 conversions
    cvt_f32_to_bf16<<<2048, 256, 0, stream>>>(x,      x_bf,  6291456 / 4);
    cvt_f32_to_bf16<<<1024, 256, 0, stream>>>(qkv_w,  w1_bf, 1769472 / 4);
    cvt_f32_to_bf16<<<576,  256, 0, stream>>>(proj_w, w2_bf,  589824 / 4);

    // QKV projection: (8192 x 768) x (2304 x 768)^T -> q,k (B,nh,N,hd); v (B,nh,hd,N)
    gemm_bt<0><<<dim3(18, 64), 256, 0, stream>>>(x_bf, w1_bf, qkv_b, qkv_sep,
                                                 8192, 2304, 768);

    // flash attention -> att (B, N, 768) bf16
    attn_fwd<<<dim3(32, 24), 256, 0, stream>>>(qkv_sep, att);

    // output projection: (8192 x 768) x (768 x 768)^T -> fp32 out
    gemm_bt<1><<<dim3(6, 64), 256, 0, stream>>>(att, w2_bf, proj_b, out,
                                                8192, 768, 768);
}

// Round 3
// 318.917 us; speedup vs baseline: 1.7228x; 1.6588x over previous
//
#include <hip/hip_runtime.h>
#include <hip/hip_bf16.h>

#define LOG2E 1.44269504088896340736f

typedef __attribute__((ext_vector_type(8))) short short8;
typedef __attribute__((ext_vector_type(4))) short short4v;
typedef __attribute__((ext_vector_type(4))) float f32x4;

__device__ __forceinline__ unsigned short f2bf(float f) {
    unsigned int u = __float_as_uint(f);
    u += 0x7fffu + ((u >> 16) & 1u);
    return (unsigned short)(u >> 16);
}

__device__ __forceinline__ unsigned cvt_pk_bf16(float a, float b) {
    unsigned r;
    asm("v_cvt_pk_bf16_f32 %0, %1, %2" : "=v"(r) : "v"(a), "v"(b));
    return r;   // low16 = bf16(a), high16 = bf16(b)
}

__device__ __forceinline__ float fast_exp2(float x) {
    float r;
    asm("v_exp_f32 %0, %1" : "=v"(r) : "v"(x));
    return r;
}

// ---------------- fp32 -> bf16 conversion ----------------
__global__ void cvt_f32_to_bf16(const float* __restrict__ in,
                                unsigned short* __restrict__ out, int n4) {
    int stride = gridDim.x * blockDim.x;
    for (int i = blockIdx.x * blockDim.x + threadIdx.x; i < n4; i += stride) {
        float4 v = ((const float4*)in)[i];
        ushort4 o;
        o.x = f2bf(v.x); o.y = f2bf(v.y); o.z = f2bf(v.z); o.w = f2bf(v.w);
        ((ushort4*)out)[i] = o;
    }
}

// ---------------- GEMM: C[m][n] = sum_k A[m][k]*B[n][k] (+bias) ----------------
// EPI==0: scatter to qkv_sep; Q (pre-scaled by 0.125*log2e), K as (B,nh,N,hd);
//         V stored (B,nh,hd,N) transposed.   EPI==1: fp32 out (M x N).
template <int EPI>
__global__ __launch_bounds__(256, 2)
void gemm_bt(const unsigned short* __restrict__ A,
             const unsigned short* __restrict__ B,
             const float* __restrict__ bias,
             void* __restrict__ Cout,
             int M, int N, int K) {
    __shared__ unsigned short As[128][72];
    __shared__ unsigned short Bs[128][72];

    const int tid  = threadIdx.x;
    const int wave = tid >> 6, lane = tid & 63;
    const int fr = lane & 15, fg = lane >> 4;
    const int wm = (wave >> 1) * 64, wn = (wave & 1) * 64;
    const int m0 = blockIdx.y * 128, n0 = blockIdx.x * 128;
    const int trow = tid >> 3, tseg = tid & 7;

    f32x4 acc[4][4];
#pragma unroll
    for (int m = 0; m < 4; m++)
#pragma unroll
        for (int n = 0; n < 4; n++) acc[m][n] = (f32x4){0.f, 0.f, 0.f, 0.f};

    for (int k0 = 0; k0 < K; k0 += 64) {
        __syncthreads();
#pragma unroll
        for (int c = 0; c < 4; c++) {
            int r = trow + c * 32;
            *(short8*)&As[r][tseg * 8] =
                *(const short8*)(A + (size_t)(m0 + r) * K + k0 + tseg * 8);
            *(short8*)&Bs[r][tseg * 8] =
                *(const short8*)(B + (size_t)(n0 + r) * K + k0 + tseg * 8);
        }
        __syncthreads();
#pragma unroll
        for (int ks = 0; ks < 2; ks++) {
            short8 af[4], bfr[4];
#pragma unroll
            for (int m = 0; m < 4; m++)
                af[m] = *(const short8*)&As[wm + m * 16 + fr][ks * 32 + fg * 8];
#pragma unroll
            for (int n = 0; n < 4; n++)
                bfr[n] = *(const short8*)&Bs[wn + n * 16 + fr][ks * 32 + fg * 8];
#pragma unroll
            for (int m = 0; m < 4; m++)
#pragma unroll
                for (int n = 0; n < 4; n++)
                    acc[m][n] = __builtin_amdgcn_mfma_f32_16x16x32_bf16(
                        af[m], bfr[n], acc[m][n], 0, 0, 0);
        }
    }

#pragma unroll
    for (int m = 0; m < 4; m++) {
#pragma unroll
        for (int n = 0; n < 4; n++) {
            int gn = n0 + wn + n * 16 + fr;
            float bv = bias[gn];
#pragma unroll
            for (int j = 0; j < 4; j++) {
                int gm = m0 + wm + m * 16 + fg * 4 + j;
                float v = acc[m][n][j] + bv;
                if (EPI == 0) {
                    int which = gn / 768, rem = gn % 768;
                    int h = rem >> 6, d = rem & 63;
                    int b = gm >> 12, nn = gm & 4095;
                    if (which == 0) v *= (0.125f * LOG2E);   // fold softmax scale into Q
                    unsigned short* o = (unsigned short*)Cout;
                    size_t base = (((size_t)which * 2 + b) * 12 + h) * 262144;
                    if (which == 2)
                        o[base + (size_t)d * 4096 + nn] = f2bf(v);   // V^T: (hd, N)
                    else
                        o[base + (size_t)nn * 64 + d] = f2bf(v);     // Q,K: (N, hd)
                } else {
                    float* o = (float*)Cout;
                    o[(size_t)gm * 768 + gn] = v;
                }
            }
        }
    }
}

// ---------------- Flash attention (swapped-operand, all-register softmax) ----
// S^T = mfma(K, Q): lane holds P[k-col][q=fr] column-local -> local reduces.
// O^T = mfma(V^T, P): corr & 1/l stay lane-local. P refragmented in-register
// via k-permutation trick (K rows loaded at phi(fr) = swap bits 2<->3).
__global__ __launch_bounds__(256, 2)
void attn_fwd(const unsigned short* __restrict__ qkv,
              unsigned short* __restrict__ outp) {
    __shared__ unsigned short Ks[64][72];
    __shared__ unsigned short Vt[64][72];        // Vt[d][k]

    const int tid  = threadIdx.x;
    const int wave = tid >> 6, lane = tid & 63;
    const int fr = lane & 15, fg = lane >> 4;
    const int frp = (fr & 3) | ((fr & 4) << 1) | ((fr & 8) >> 1); // swap bits 2<->3
    const int fgl = fg & 1, fgh = fg >> 1;

    const int qt = blockIdx.x;        // q tile 0..31
    const int bh = blockIdx.y;        // 0..23
    const int b = bh / 12, h = bh % 12;

    const size_t headsz = (size_t)4096 * 64;
    const unsigned short* qh  = qkv + ((size_t)b * 12 + h) * headsz;
    const unsigned short* kh  = qkv + ((size_t)(2 + b) * 12 + h) * headsz;
    const unsigned short* vht = qkv + ((size_t)(4 + b) * 12 + h) * headsz; // (hd,N)

    const int qw = qt * 128 + wave * 32;

    // Q fragments (already scaled by 0.125*log2e in GEMM epilogue)
    short8 qf[2][2];
#pragma unroll
    for (int qm = 0; qm < 2; qm++)
#pragma unroll
        for (int ks = 0; ks < 2; ks++)
            qf[qm][ks] = *(const short8*)(qh + (size_t)(qw + qm * 16 + fr) * 64 +
                                          ks * 32 + fg * 8);

    float mrow[2] = {-1e30f, -1e30f}, lrow[2] = {0.f, 0.f};
    f32x4 accO[4][2];                 // O^T[d = 16df+4fg+j][q = 16qm+fr]
#pragma unroll
    for (int df = 0; df < 4; df++)
#pragma unroll
        for (int qm = 0; qm < 2; qm++) accO[df][qm] = (f32x4){0.f, 0.f, 0.f, 0.f};

    const int r = tid >> 3, sg = tid & 7;

    for (int kt = 0; kt < 64; kt++) {
        __syncthreads();
        const unsigned short* kb = kh + (size_t)kt * 4096;
#pragma unroll
        for (int c = 0; c < 2; c++) {
            int kr = r + c * 32;
            *(short8*)&Ks[kr][sg * 8] = *(const short8*)(kb + kr * 64 + sg * 8);
            *(short8*)&Vt[kr][sg * 8] =
                *(const short8*)(vht + (size_t)kr * 4096 + kt * 64 + sg * 8);
        }
        __syncthreads();

        // S^T[k'][q], k' = 16nf + 8(fg&1) + 4(fg>>1) + j  (via frp row permutation)
        f32x4 s[4][2];
#pragma unroll
        for (int nf = 0; nf < 4; nf++)
#pragma unroll
            for (int qm = 0; qm < 2; qm++) s[nf][qm] = (f32x4){0.f, 0.f, 0.f, 0.f};
#pragma unroll
        for (int ks = 0; ks < 2; ks++) {
            short8 kf[4];
#pragma unroll
            for (int nf = 0; nf < 4; nf++)
                kf[nf] = *(const short8*)&Ks[nf * 16 + frp][ks * 32 + fg * 8];
#pragma unroll
            for (int nf = 0; nf < 4; nf++)
#pragma unroll
                for (int qm = 0; qm < 2; qm++)
                    s[nf][qm] = __builtin_amdgcn_mfma_f32_16x16x32_bf16(
                        kf[nf], qf[qm][ks], s[nf][qm], 0, 0, 0);
        }

        // online softmax: entire q-column is (this lane x 3 partners via xor16/32)
        unsigned P2[2][4][2];
#pragma unroll
        for (int qm = 0; qm < 2; qm++) {
            float mx = s[0][qm][0];
#pragma unroll
            for (int nf = 0; nf < 4; nf++)
#pragma unroll
                for (int j = 0; j < 4; j++)
                    if (nf | j) mx = fmaxf(mx, s[nf][qm][j]);
            mx = fmaxf(mx, __shfl_xor(mx, 16));
            mx = fmaxf(mx, __shfl_xor(mx, 32));
            float mnew = fmaxf(mrow[qm], mx);
            float corr = fast_exp2(mrow[qm] - mnew);
            mrow[qm] = mnew;
            float rs = 0.f;
#pragma unroll
            for (int nf = 0; nf < 4; nf++)
#pragma unroll
                for (int j = 0; j < 4; j++) {
                    float p = fast_exp2(s[nf][qm][j] - mnew);
                    s[nf][qm][j] = p;
                    rs += p;
                }
            rs += __shfl_xor(rs, 16);
            rs += __shfl_xor(rs, 32);
            lrow[qm] = lrow[qm] * corr + rs;
#pragma unroll
            for (int df = 0; df < 4; df++) accO[df][qm] *= corr;
#pragma unroll
            for (int nf = 0; nf < 4; nf++) {
                P2[qm][nf][0] = cvt_pk_bf16(s[nf][qm][0], s[nf][qm][1]);
                P2[qm][nf][1] = cvt_pk_bf16(s[nf][qm][2], s[nf][qm][3]);
            }
        }

        // O^T += V~ . P : vf columns permuted to match P's per-lane k order
#pragma unroll
        for (int ks = 0; ks < 2; ks++) {
            const int cb = ks * 32 + fgl * 8 + fgh * 4;
            short8 pf[2];
#pragma unroll
            for (int qm = 0; qm < 2; qm++) {
                union { unsigned w[4]; short8 v; } u;
                u.w[0] = P2[qm][2 * ks][0];     u.w[1] = P2[qm][2 * ks][1];
                u.w[2] = P2[qm][2 * ks + 1][0]; u.w[3] = P2[qm][2 * ks + 1][1];
                pf[qm] = u.v;
            }
#pragma unroll
            for (int df = 0; df < 4; df++) {
                union { short4v hh[2]; short8 v; } uv;
                uv.hh[0] = *(const short4v*)&Vt[df * 16 + fr][cb];
                uv.hh[1] = *(const short4v*)&Vt[df * 16 + fr][cb + 16];
#pragma unroll
                for (int qm = 0; qm < 2; qm++)
                    accO[df][qm] = __builtin_amdgcn_mfma_f32_16x16x32_bf16(
                        uv.v, pf[qm], accO[df][qm], 0, 0, 0);
            }
        }
    }

    // epilogue: lane-local 1/l, O^T -> out (B, N, 768) bf16
#pragma unroll
    for (int qm = 0; qm < 2; qm++) {
        float inv = 1.0f / lrow[qm];
        int gq = qw + qm * 16 + fr;
        size_t rowoff = (size_t)(b * 4096 + gq) * 768 + h * 64;
#pragma unroll
        for (int df = 0; df < 4; df++) {
            ushort4 o;
            o.x = f2bf(accO[df][qm][0] * inv);
            o.y = f2bf(accO[df][qm][1] * inv);
            o.z = f2bf(accO[df][qm][2] * inv);
            o.w = f2bf(accO[df][qm][3] * inv);
            *(ushort4*)(outp + rowoff + df * 16 + fg * 4) = o;
        }
    }
}

// ---------------- launch ----------------
extern "C" void kernel_launch(void* const* d_in, const int* in_sizes, int n_in,
                              void* d_out, int out_size, void* d_ws, size_t ws_size,
                              hipStream_t stream) {
    const float* x      = (const float*)d_in[0];
    const float* qkv_w  = (const float*)d_in[1];
    const float* qkv_b  = (const float*)d_in[2];
    const float* proj_w = (const float*)d_in[3];
    const float* proj_b = (const float*)d_in[4];
    float* out = (float*)d_out;

    char* ws = (char*)d_ws;
    unsigned short* x_bf    = (unsigned short*)(ws);              // 12,582,912 B
    unsigned short* w1_bf   = (unsigned short*)(ws + 12582912);   //  3,538,944 B
    unsigned short* w2_bf   = (unsigned short*)(ws + 16121856);   //  1,179,648 B
    unsigned short* qkv_sep = (unsigned short*)(ws + 17301504);   // 37,748,736 B
    unsigned short* att     = (unsigned short*)(ws + 55050240);   // 12,582,912 B

    cvt_f32_to_bf16<<<2048, 256, 0, stream>>>(x,      x_bf,  6291456 / 4);
    cvt_f32_to_bf16<<<1024, 256, 0, stream>>>(qkv_w,  w1_bf, 1769472 / 4);
    cvt_f32_to_bf16<<<576,  256, 0, stream>>>(proj_w, w2_bf,  589824 / 4);

    gemm_bt<0><<<dim3(18, 64), 256, 0, stream>>>(x_bf, w1_bf, qkv_b, qkv_sep,
                                                 8192, 2304, 768);

    attn_fwd<<<dim3(32, 24), 256, 0, stream>>>(qkv_sep, att);

    gemm_bt<1><<<dim3(6, 64), 256, 0, stream>>>(att, w2_bf, proj_b, out,
                                                8192, 768, 768);
}

// Round 4
// 236.647 us; speedup vs baseline: 2.3218x; 1.3476x over previous
//
#include <hip/hip_runtime.h>
#include <hip/hip_bf16.h>

#define LOG2E 1.44269504088896340736f

typedef __attribute__((ext_vector_type(8))) short short8;
typedef __attribute__((ext_vector_type(4))) float f32x4;

__device__ __forceinline__ unsigned short f2bf(float f) {
    unsigned int u = __float_as_uint(f);
    u += 0x7fffu + ((u >> 16) & 1u);
    return (unsigned short)(u >> 16);
}

__device__ __forceinline__ unsigned cvt_pk_bf16(float a, float b) {
    unsigned r;
    asm("v_cvt_pk_bf16_f32 %0, %1, %2" : "=v"(r) : "v"(a), "v"(b));
    return r;   // low16 = bf16(a), high16 = bf16(b)
}

__device__ __forceinline__ float fast_exp2(float x) {
    float r;
    asm("v_exp_f32 %0, %1" : "=v"(r) : "v"(x));
    return r;
}

// ---------------- fp32 -> bf16 conversion ----------------
__global__ void cvt_f32_to_bf16(const float* __restrict__ in,
                                unsigned short* __restrict__ out, int n4) {
    int stride = gridDim.x * blockDim.x;
    for (int i = blockIdx.x * blockDim.x + threadIdx.x; i < n4; i += stride) {
        float4 v = ((const float4*)in)[i];
        ushort4 o;
        o.x = f2bf(v.x); o.y = f2bf(v.y); o.z = f2bf(v.z); o.w = f2bf(v.w);
        ((ushort4*)out)[i] = o;
    }
}

// ---------------- GEMM: C[m][n] = sum_k A[m][k]*B[n][k] (+bias) ----------------
// Split-stage pipelined: loads for tile t+1 issued before compute of tile t.
// EPI==0: scatter to qkv_sep; Q pre-scaled by 0.125*log2e, K as (B,nh,N,hd);
//         V stored (B,nh,hd,N) transposed with k-bits permuted per 64-tile.
// EPI==1: fp32 out (M x N).
template <int EPI>
__global__ __launch_bounds__(256, 2)
void gemm_bt(const unsigned short* __restrict__ A,
             const unsigned short* __restrict__ B,
             const float* __restrict__ bias,
             void* __restrict__ Cout,
             int M, int N, int K) {
    __shared__ unsigned short As[128][72];
    __shared__ unsigned short Bs[128][72];

    const int tid  = threadIdx.x;
    const int wave = tid >> 6, lane = tid & 63;
    const int fr = lane & 15, fg = lane >> 4;
    const int wm = (wave >> 1) * 64, wn = (wave & 1) * 64;
    const int m0 = blockIdx.y * 128, n0 = blockIdx.x * 128;
    const int trow = tid >> 3, tseg = tid & 7;

    f32x4 acc[4][4];
#pragma unroll
    for (int m = 0; m < 4; m++)
#pragma unroll
        for (int n = 0; n < 4; n++) acc[m][n] = (f32x4){0.f, 0.f, 0.f, 0.f};

    short8 rA[4], rB[4];
#pragma unroll
    for (int c = 0; c < 4; c++) {
        int r = trow + c * 32;
        rA[c] = *(const short8*)(A + (size_t)(m0 + r) * K + tseg * 8);
        rB[c] = *(const short8*)(B + (size_t)(n0 + r) * K + tseg * 8);
    }

    for (int k0 = 0; k0 < K; k0 += 64) {
        __syncthreads();
#pragma unroll
        for (int c = 0; c < 4; c++) {
            int r = trow + c * 32;
            *(short8*)&As[r][tseg * 8] = rA[c];
            *(short8*)&Bs[r][tseg * 8] = rB[c];
        }
        if (k0 + 64 < K) {
#pragma unroll
            for (int c = 0; c < 4; c++) {
                int r = trow + c * 32;
                rA[c] = *(const short8*)(A + (size_t)(m0 + r) * K + k0 + 64 + tseg * 8);
                rB[c] = *(const short8*)(B + (size_t)(n0 + r) * K + k0 + 64 + tseg * 8);
            }
        }
        __syncthreads();
#pragma unroll
        for (int ks = 0; ks < 2; ks++) {
            short8 af[4], bfr[4];
#pragma unroll
            for (int m = 0; m < 4; m++)
                af[m] = *(const short8*)&As[wm + m * 16 + fr][ks * 32 + fg * 8];
#pragma unroll
            for (int n = 0; n < 4; n++)
                bfr[n] = *(const short8*)&Bs[wn + n * 16 + fr][ks * 32 + fg * 8];
#pragma unroll
            for (int m = 0; m < 4; m++)
#pragma unroll
                for (int n = 0; n < 4; n++)
                    acc[m][n] = __builtin_amdgcn_mfma_f32_16x16x32_bf16(
                        af[m], bfr[n], acc[m][n], 0, 0, 0);
        }
    }

#pragma unroll
    for (int m = 0; m < 4; m++) {
#pragma unroll
        for (int n = 0; n < 4; n++) {
            int gn = n0 + wn + n * 16 + fr;
            float bv = bias[gn];
#pragma unroll
            for (int j = 0; j < 4; j++) {
                int gm = m0 + wm + m * 16 + fg * 4 + j;
                float v = acc[m][n][j] + bv;
                if (EPI == 0) {
                    int which = gn / 768, rem = gn % 768;
                    int h = rem >> 6, d = rem & 63;
                    int b = gm >> 12, nn = gm & 4095;
                    if (which == 0) v *= (0.125f * LOG2E);   // fold softmax scale into Q
                    unsigned short* o = (unsigned short*)Cout;
                    size_t base = (((size_t)which * 2 + b) * 12 + h) * 262144;
                    if (which == 2) {
                        // V^T (hd, N), k-bits permuted within each 64-tile:
                        // p_b4 = k_b3, p_b3 = k_b2, p_b2 = k_b4
                        int k6 = nn & 63;
                        int kp = (k6 & 0x23) | ((k6 & 0x08) << 1) |
                                 ((k6 & 0x04) << 1) | ((k6 & 0x10) >> 2);
                        o[base + (size_t)d * 4096 + (nn & ~63) + kp] = f2bf(v);
                    } else {
                        o[base + (size_t)nn * 64 + d] = f2bf(v);     // Q,K: (N, hd)
                    }
                } else {
                    float* o = (float*)Cout;
                    o[(size_t)gm * 768 + gn] = v;
                }
            }
        }
    }
}

// ---------------- Flash attention (swapped-operand, pipelined) ----------------
__global__ __launch_bounds__(256, 2)
void attn_fwd(const unsigned short* __restrict__ qkv,
              unsigned short* __restrict__ outp) {
    __shared__ unsigned short Ks[64][72];
    __shared__ unsigned short Vt[64][72];        // Vt[d][p(k)]

    const int tid  = threadIdx.x;
    const int wave = tid >> 6, lane = tid & 63;
    const int fr = lane & 15, fg = lane >> 4;
    const int frp = (fr & 3) | ((fr & 4) << 1) | ((fr & 8) >> 1); // swap bits 2<->3
    const int fgl = fg & 1, fgh = fg >> 1;

    const int qt = blockIdx.x;        // q tile 0..31
    const int bh = blockIdx.y;        // 0..23
    const int b = bh / 12, h = bh % 12;

    const size_t headsz = (size_t)4096 * 64;
    const unsigned short* qh  = qkv + ((size_t)b * 12 + h) * headsz;
    const unsigned short* kh  = qkv + ((size_t)(2 + b) * 12 + h) * headsz;
    const unsigned short* vht = qkv + ((size_t)(4 + b) * 12 + h) * headsz; // (hd,N) perm

    const int qw = qt * 128 + wave * 32;

    // Q fragments (already scaled by 0.125*log2e in GEMM epilogue)
    short8 qf[2][2];
#pragma unroll
    for (int qm = 0; qm < 2; qm++)
#pragma unroll
        for (int ks = 0; ks < 2; ks++)
            qf[qm][ks] = *(const short8*)(qh + (size_t)(qw + qm * 16 + fr) * 64 +
                                          ks * 32 + fg * 8);

    float mrow[2] = {-1e30f, -1e30f}, lrow[2] = {0.f, 0.f};
    f32x4 accO[4][2];                 // O^T[d = 16df+4fg+j][q = 16qm+fr]
#pragma unroll
    for (int df = 0; df < 4; df++)
#pragma unroll
        for (int qm = 0; qm < 2; qm++) accO[df][qm] = (f32x4){0.f, 0.f, 0.f, 0.f};

    const int r = tid >> 3, sg = tid & 7;

    // pipeline prologue: loads for tile 0
    short8 rK[2], rV[2];
#pragma unroll
    for (int c = 0; c < 2; c++) {
        int kr = r + c * 32;
        rK[c] = *(const short8*)(kh + (size_t)kr * 64 + sg * 8);
        rV[c] = *(const short8*)(vht + (size_t)kr * 4096 + sg * 8);
    }

    for (int kt = 0; kt < 64; kt++) {
        __syncthreads();
#pragma unroll
        for (int c = 0; c < 2; c++) {
            int kr = r + c * 32;
            *(short8*)&Ks[kr][sg * 8] = rK[c];
            *(short8*)&Vt[kr][sg * 8] = rV[c];
        }
        if (kt < 63) {
            const unsigned short* kb = kh + (size_t)(kt + 1) * 4096;
#pragma unroll
            for (int c = 0; c < 2; c++) {
                int kr = r + c * 32;
                rK[c] = *(const short8*)(kb + kr * 64 + sg * 8);
                rV[c] = *(const short8*)(vht + (size_t)kr * 4096 + (kt + 1) * 64 + sg * 8);
            }
        }
        __syncthreads();

        // S^T[k'][q], k' = 16nf + 8fgl + 4fgh + j  (via frp row permutation)
        f32x4 s[4][2];
#pragma unroll
        for (int nf = 0; nf < 4; nf++)
#pragma unroll
            for (int qm = 0; qm < 2; qm++) s[nf][qm] = (f32x4){0.f, 0.f, 0.f, 0.f};
        __builtin_amdgcn_s_setprio(1);
#pragma unroll
        for (int ks = 0; ks < 2; ks++) {
            short8 kf[4];
#pragma unroll
            for (int nf = 0; nf < 4; nf++)
                kf[nf] = *(const short8*)&Ks[nf * 16 + frp][ks * 32 + fg * 8];
#pragma unroll
            for (int nf = 0; nf < 4; nf++)
#pragma unroll
                for (int qm = 0; qm < 2; qm++)
                    s[nf][qm] = __builtin_amdgcn_mfma_f32_16x16x32_bf16(
                        kf[nf], qf[qm][ks], s[nf][qm], 0, 0, 0);
        }
        __builtin_amdgcn_s_setprio(0);

        // online softmax, exp2 domain, defer-max (THR=8)
        unsigned P2[2][4][2];
#pragma unroll
        for (int qm = 0; qm < 2; qm++) {
            float mx = s[0][qm][0];
#pragma unroll
            for (int nf = 0; nf < 4; nf++)
#pragma unroll
                for (int j = 0; j < 4; j++)
                    if (nf | j) mx = fmaxf(mx, s[nf][qm][j]);
            mx = fmaxf(mx, __shfl_xor(mx, 16));
            mx = fmaxf(mx, __shfl_xor(mx, 32));
            if (__all(mx - mrow[qm] <= 8.0f)) {
                // deferred: keep old max, no rescale (P bounded by 2^8)
                float rs = 0.f;
#pragma unroll
                for (int nf = 0; nf < 4; nf++)
#pragma unroll
                    for (int j = 0; j < 4; j++) {
                        float p = fast_exp2(s[nf][qm][j] - mrow[qm]);
                        s[nf][qm][j] = p;
                        rs += p;
                    }
                rs += __shfl_xor(rs, 16);
                rs += __shfl_xor(rs, 32);
                lrow[qm] += rs;
            } else {
                float mnew = fmaxf(mrow[qm], mx);
                float corr = fast_exp2(mrow[qm] - mnew);
                mrow[qm] = mnew;
                float rs = 0.f;
#pragma unroll
                for (int nf = 0; nf < 4; nf++)
#pragma unroll
                    for (int j = 0; j < 4; j++) {
                        float p = fast_exp2(s[nf][qm][j] - mnew);
                        s[nf][qm][j] = p;
                        rs += p;
                    }
                rs += __shfl_xor(rs, 16);
                rs += __shfl_xor(rs, 32);
                lrow[qm] = lrow[qm] * corr + rs;
#pragma unroll
                for (int df = 0; df < 4; df++) accO[df][qm] *= corr;
            }
#pragma unroll
            for (int nf = 0; nf < 4; nf++) {
                P2[qm][nf][0] = cvt_pk_bf16(s[nf][qm][0], s[nf][qm][1]);
                P2[qm][nf][1] = cvt_pk_bf16(s[nf][qm][2], s[nf][qm][3]);
            }
        }

        // O^T += V~ . P : V read b128 from pre-permuted layout
        __builtin_amdgcn_s_setprio(1);
#pragma unroll
        for (int ks = 0; ks < 2; ks++) {
            short8 pf[2];
#pragma unroll
            for (int qm = 0; qm < 2; qm++) {
                union { unsigned w[4]; short8 v; } u;
                u.w[0] = P2[qm][2 * ks][0];     u.w[1] = P2[qm][2 * ks][1];
                u.w[2] = P2[qm][2 * ks + 1][0]; u.w[3] = P2[qm][2 * ks + 1][1];
                pf[qm] = u.v;
            }
#pragma unroll
            for (int df = 0; df < 4; df++) {
                short8 vf = *(const short8*)&Vt[df * 16 + fr][ks * 32 + fgl * 16 + fgh * 8];
#pragma unroll
                for (int qm = 0; qm < 2; qm++)
                    accO[df][qm] = __builtin_amdgcn_mfma_f32_16x16x32_bf16(
                        vf, pf[qm], accO[df][qm], 0, 0, 0);
            }
        }
        __builtin_amdgcn_s_setprio(0);
    }

    // epilogue: lane-local 1/l, O^T -> out (B, N, 768) bf16
#pragma unroll
    for (int qm = 0; qm < 2; qm++) {
        float inv = 1.0f / lrow[qm];
        int gq = qw + qm * 16 + fr;
        size_t rowoff = (size_t)(b * 4096 + gq) * 768 + h * 64;
#pragma unroll
        for (int df = 0; df < 4; df++) {
            ushort4 o;
            o.x = f2bf(accO[df][qm][0] * inv);
            o.y = f2bf(accO[df][qm][1] * inv);
            o.z = f2bf(accO[df][qm][2] * inv);
            o.w = f2bf(accO[df][qm][3] * inv);
            *(ushort4*)(outp + rowoff + df * 16 + fg * 4) = o;
        }
    }
}

// ---------------- launch ----------------
extern "C" void kernel_launch(void* const* d_in, const int* in_sizes, int n_in,
                              void* d_out, int out_size, void* d_ws, size_t ws_size,
                              hipStream_t stream) {
    const float* x      = (const float*)d_in[0];
    const float* qkv_w  = (const float*)d_in[1];
    const float* qkv_b  = (const float*)d_in[2];
    const float* proj_w = (const float*)d_in[3];
    const float* proj_b = (const float*)d_in[4];
    float* out = (float*)d_out;

    char* ws = (char*)d_ws;
    unsigned short* x_bf    = (unsigned short*)(ws);              // 12,582,912 B
    unsigned short* w1_bf   = (unsigned short*)(ws + 12582912);   //  3,538,944 B
    unsigned short* w2_bf   = (unsigned short*)(ws + 16121856);   //  1,179,648 B
    unsigned short* qkv_sep = (unsigned short*)(ws + 17301504);   // 37,748,736 B
    unsigned short* att     = (unsigned short*)(ws + 55050240);   // 12,582,912 B

    cvt_f32_to_bf16<<<2048, 256, 0, stream>>>(x,      x_bf,  6291456 / 4);
    cvt_f32_to_bf16<<<1024, 256, 0, stream>>>(qkv_w,  w1_bf, 1769472 / 4);
    cvt_f32_to_bf16<<<576,  256, 0, stream>>>(proj_w, w2_bf,  589824 / 4);

    gemm_bt<0><<<dim3(18, 64), 256, 0, stream>>>(x_bf, w1_bf, qkv_b, qkv_sep,
                                                 8192, 2304, 768);

    attn_fwd<<<dim3(32, 24), 256, 0, stream>>>(qkv_sep, att);

    gemm_bt<1><<<dim3(6, 64), 256, 0, stream>>>(att, w2_bf, proj_b, out,
                                                8192, 768, 768);
}

// Round 5
// 226.268 us; speedup vs baseline: 2.4283x; 1.0459x over previous
//
#include <hip/hip_runtime.h>
#include <hip/hip_bf16.h>

#define LOG2E 1.44269504088896340736f

typedef __attribute__((ext_vector_type(8))) short short8;
typedef __attribute__((ext_vector_type(4))) float f32x4;
typedef __attribute__((ext_vector_type(16))) float f32x16;

__device__ __forceinline__ unsigned short f2bf(float f) {
    unsigned int u = __float_as_uint(f);
    u += 0x7fffu + ((u >> 16) & 1u);
    return (unsigned short)(u >> 16);
}

__device__ __forceinline__ unsigned cvt_pk_bf16(float a, float b) {
    unsigned r;
    asm("v_cvt_pk_bf16_f32 %0, %1, %2" : "=v"(r) : "v"(a), "v"(b));
    return r;   // low16 = bf16(a), high16 = bf16(b)
}

__device__ __forceinline__ float fast_exp2(float x) {
    float r;
    asm("v_exp_f32 %0, %1" : "=v"(r) : "v"(x));
    return r;
}

// ---------------- fp32 -> bf16 conversion ----------------
__global__ void cvt_f32_to_bf16(const float* __restrict__ in,
                                unsigned short* __restrict__ out, int n4) {
    int stride = gridDim.x * blockDim.x;
    for (int i = blockIdx.x * blockDim.x + threadIdx.x; i < n4; i += stride) {
        float4 v = ((const float4*)in)[i];
        ushort4 o;
        o.x = f2bf(v.x); o.y = f2bf(v.y); o.z = f2bf(v.z); o.w = f2bf(v.w);
        ((ushort4*)out)[i] = o;
    }
}

// ---------------- GEMM: C[m][n] = sum_k A[m][k]*B[n][k] (+bias) ----------------
// Split-stage pipelined: loads for tile t+1 issued before compute of tile t.
// EPI==0: scatter to qkv_sep; Q pre-scaled by 0.125*log2e, K as (B,nh,N,hd);
//         V stored (B,nh,hd,N) plain-transposed.
// EPI==1: fp32 out (M x N).
template <int EPI>
__global__ __launch_bounds__(256, 2)
void gemm_bt(const unsigned short* __restrict__ A,
             const unsigned short* __restrict__ B,
             const float* __restrict__ bias,
             void* __restrict__ Cout,
             int M, int N, int K) {
    __shared__ unsigned short As[128][72];
    __shared__ unsigned short Bs[128][72];

    const int tid  = threadIdx.x;
    const int wave = tid >> 6, lane = tid & 63;
    const int fr = lane & 15, fg = lane >> 4;
    const int wm = (wave >> 1) * 64, wn = (wave & 1) * 64;
    const int m0 = blockIdx.y * 128, n0 = blockIdx.x * 128;
    const int trow = tid >> 3, tseg = tid & 7;

    f32x4 acc[4][4];
#pragma unroll
    for (int m = 0; m < 4; m++)
#pragma unroll
        for (int n = 0; n < 4; n++) acc[m][n] = (f32x4){0.f, 0.f, 0.f, 0.f};

    short8 rA[4], rB[4];
#pragma unroll
    for (int c = 0; c < 4; c++) {
        int r = trow + c * 32;
        rA[c] = *(const short8*)(A + (size_t)(m0 + r) * K + tseg * 8);
        rB[c] = *(const short8*)(B + (size_t)(n0 + r) * K + tseg * 8);
    }

    for (int k0 = 0; k0 < K; k0 += 64) {
        __syncthreads();
#pragma unroll
        for (int c = 0; c < 4; c++) {
            int r = trow + c * 32;
            *(short8*)&As[r][tseg * 8] = rA[c];
            *(short8*)&Bs[r][tseg * 8] = rB[c];
        }
        if (k0 + 64 < K) {
#pragma unroll
            for (int c = 0; c < 4; c++) {
                int r = trow + c * 32;
                rA[c] = *(const short8*)(A + (size_t)(m0 + r) * K + k0 + 64 + tseg * 8);
                rB[c] = *(const short8*)(B + (size_t)(n0 + r) * K + k0 + 64 + tseg * 8);
            }
        }
        __syncthreads();
#pragma unroll
        for (int ks = 0; ks < 2; ks++) {
            short8 af[4], bfr[4];
#pragma unroll
            for (int m = 0; m < 4; m++)
                af[m] = *(const short8*)&As[wm + m * 16 + fr][ks * 32 + fg * 8];
#pragma unroll
            for (int n = 0; n < 4; n++)
                bfr[n] = *(const short8*)&Bs[wn + n * 16 + fr][ks * 32 + fg * 8];
#pragma unroll
            for (int m = 0; m < 4; m++)
#pragma unroll
                for (int n = 0; n < 4; n++)
                    acc[m][n] = __builtin_amdgcn_mfma_f32_16x16x32_bf16(
                        af[m], bfr[n], acc[m][n], 0, 0, 0);
        }
    }

#pragma unroll
    for (int m = 0; m < 4; m++) {
#pragma unroll
        for (int n = 0; n < 4; n++) {
            int gn = n0 + wn + n * 16 + fr;
            float bv = bias[gn];
#pragma unroll
            for (int j = 0; j < 4; j++) {
                int gm = m0 + wm + m * 16 + fg * 4 + j;
                float v = acc[m][n][j] + bv;
                if (EPI == 0) {
                    int which = gn / 768, rem = gn % 768;
                    int h = rem >> 6, d = rem & 63;
                    int b = gm >> 12, nn = gm & 4095;
                    if (which == 0) v *= (0.125f * LOG2E);   // fold softmax scale into Q
                    unsigned short* o = (unsigned short*)Cout;
                    size_t base = (((size_t)which * 2 + b) * 12 + h) * 262144;
                    if (which == 2)
                        o[base + (size_t)d * 4096 + nn] = f2bf(v);   // V^T: (hd, N)
                    else
                        o[base + (size_t)nn * 64 + d] = f2bf(v);     // Q,K: (N, hd)
                } else {
                    float* o = (float*)Cout;
                    o[(size_t)gm * 768 + gn] = v;
                }
            }
        }
    }
}

// ---------------- Flash attention (32x32 MFMA, one q-row per lane) ----------
// S^T = mfma32(K_perm, Q): C col = lane&31 = q, rows = k'-slots.
// K rows loaded at pi(l31) (swap bits 2<->3) so that C k-slots line up exactly
// with PV's B-operand k-slots: pf[ks2] = pack(s[ks2>>1][8*(ks2&1)..+7]).
// O^T = mfma32(V^T, P): d rows plain, col q = lane&31, all lane-local.
__global__ __launch_bounds__(256, 2)
void attn_fwd(const unsigned short* __restrict__ qkv,
              unsigned short* __restrict__ outp) {
    __shared__ unsigned short Ks[64][72];
    __shared__ unsigned short Vt[64][72];        // plain V^T: Vt[d][k]

    const int tid  = threadIdx.x;
    const int wave = tid >> 6, lane = tid & 63;
    const int l31 = lane & 31, hh = lane >> 5;
    const int l31p = (l31 & 0x13) | ((l31 & 4) << 1) | ((l31 & 8) >> 1); // swap b2<->b3

    const int qt = blockIdx.x;        // q tile 0..31
    const int bh = blockIdx.y;        // 0..23
    const int b = bh / 12, h = bh % 12;

    const size_t headsz = (size_t)4096 * 64;
    const unsigned short* qh  = qkv + ((size_t)b * 12 + h) * headsz;
    const unsigned short* kh  = qkv + ((size_t)(2 + b) * 12 + h) * headsz;
    const unsigned short* vht = qkv + ((size_t)(4 + b) * 12 + h) * headsz; // (hd,N)

    const int qw = qt * 128 + wave * 32;
    const int gq = qw + l31;

    // Q fragments (pre-scaled by 0.125*log2e): B-operand, 4 k-steps of 16
    short8 qf[4];
#pragma unroll
    for (int ks = 0; ks < 4; ks++)
        qf[ks] = *(const short8*)(qh + (size_t)gq * 64 + ks * 16 + hh * 8);

    float mrow = -1e30f, lrow = 0.f;
    f32x16 accA = (f32x16)0.f, accB = (f32x16)0.f;  // O^T d-blocks 0..31 / 32..63

    const int r = tid >> 3, sg = tid & 7;

    // pipeline prologue: loads for tile 0
    short8 rK[2], rV[2];
#pragma unroll
    for (int c = 0; c < 2; c++) {
        int kr = r + c * 32;
        rK[c] = *(const short8*)(kh + (size_t)kr * 64 + sg * 8);
        rV[c] = *(const short8*)(vht + (size_t)kr * 4096 + sg * 8);
    }

    for (int kt = 0; kt < 64; kt++) {
        __syncthreads();
#pragma unroll
        for (int c = 0; c < 2; c++) {
            int kr = r + c * 32;
            *(short8*)&Ks[kr][sg * 8] = rK[c];
            *(short8*)&Vt[kr][sg * 8] = rV[c];
        }
        if (kt < 63) {
            const unsigned short* kb = kh + (size_t)(kt + 1) * 4096;
#pragma unroll
            for (int c = 0; c < 2; c++) {
                int kr = r + c * 32;
                rK[c] = *(const short8*)(kb + kr * 64 + sg * 8);
                rV[c] = *(const short8*)(vht + (size_t)kr * 4096 + (kt + 1) * 64 + sg * 8);
            }
        }
        __syncthreads();

        // S^T = K_perm x Q : two 32-k blocks, 4 k-steps each
        f32x16 s0 = (f32x16)0.f, s1 = (f32x16)0.f;
        __builtin_amdgcn_s_setprio(1);
#pragma unroll
        for (int ks = 0; ks < 4; ks++) {
            short8 kf0 = *(const short8*)&Ks[l31p][ks * 16 + hh * 8];
            short8 kf1 = *(const short8*)&Ks[32 + l31p][ks * 16 + hh * 8];
            s0 = __builtin_amdgcn_mfma_f32_32x32x16_bf16(kf0, qf[ks], s0, 0, 0, 0);
            s1 = __builtin_amdgcn_mfma_f32_32x32x16_bf16(kf1, qf[ks], s1, 0, 0, 0);
        }
        __builtin_amdgcn_s_setprio(0);

        // lane-local softmax over the 32 s-values (one q-row per lane)
        float t[16];
#pragma unroll
        for (int i = 0; i < 8; i++) t[i] = fmaxf(s0[2 * i], s0[2 * i + 1]);
#pragma unroll
        for (int i = 0; i < 8; i++) t[i + 8] = fmaxf(s1[2 * i], s1[2 * i + 1]);
#pragma unroll
        for (int w = 8; w; w >>= 1)
#pragma unroll
            for (int i = 0; i < 8; i++)
                if (i < w) t[i] = fmaxf(t[i], t[i + w]);
        float mx = fmaxf(t[0], __shfl_xor(t[0], 32));

        if (!__all(mx - mrow <= 8.0f)) {      // rare rescale path
            float mnew = fmaxf(mrow, mx);
            float corr = fast_exp2(mrow - mnew);
            mrow = mnew;
            lrow *= corr;
#pragma unroll
            for (int i = 0; i < 16; i++) { accA[i] *= corr; accB[i] *= corr; }
        }
#pragma unroll
        for (int i = 0; i < 16; i++) {
            s0[i] = fast_exp2(s0[i] - mrow);
            s1[i] = fast_exp2(s1[i] - mrow);
        }
#pragma unroll
        for (int i = 0; i < 8; i++) t[i] = s0[2 * i] + s0[2 * i + 1];
#pragma unroll
        for (int i = 0; i < 8; i++) t[i + 8] = s1[2 * i] + s1[2 * i + 1];
#pragma unroll
        for (int w = 8; w; w >>= 1)
#pragma unroll
            for (int i = 0; i < 8; i++)
                if (i < w) t[i] += t[i + w];
        lrow += t[0] + __shfl_xor(t[0], 32);

        // pack P: pf[ks2] covers k = 16*ks2 + 8*hh + e, from s[ks2>>1][8*(ks2&1)..]
        short8 pf[4];
        {
            union { unsigned w[4]; short8 v; } up;
            up.w[0] = cvt_pk_bf16(s0[0], s0[1]);  up.w[1] = cvt_pk_bf16(s0[2], s0[3]);
            up.w[2] = cvt_pk_bf16(s0[4], s0[5]);  up.w[3] = cvt_pk_bf16(s0[6], s0[7]);
            pf[0] = up.v;
            up.w[0] = cvt_pk_bf16(s0[8], s0[9]);  up.w[1] = cvt_pk_bf16(s0[10], s0[11]);
            up.w[2] = cvt_pk_bf16(s0[12], s0[13]); up.w[3] = cvt_pk_bf16(s0[14], s0[15]);
            pf[1] = up.v;
            up.w[0] = cvt_pk_bf16(s1[0], s1[1]);  up.w[1] = cvt_pk_bf16(s1[2], s1[3]);
            up.w[2] = cvt_pk_bf16(s1[4], s1[5]);  up.w[3] = cvt_pk_bf16(s1[6], s1[7]);
            pf[2] = up.v;
            up.w[0] = cvt_pk_bf16(s1[8], s1[9]);  up.w[1] = cvt_pk_bf16(s1[10], s1[11]);
            up.w[2] = cvt_pk_bf16(s1[12], s1[13]); up.w[3] = cvt_pk_bf16(s1[14], s1[15]);
            pf[3] = up.v;
        }

        // O^T += V^T x P
        __builtin_amdgcn_s_setprio(1);
#pragma unroll
        for (int ks2 = 0; ks2 < 4; ks2++) {
            short8 vf0 = *(const short8*)&Vt[l31][ks2 * 16 + hh * 8];
            short8 vf1 = *(const short8*)&Vt[32 + l31][ks2 * 16 + hh * 8];
            accA = __builtin_amdgcn_mfma_f32_32x32x16_bf16(vf0, pf[ks2], accA, 0, 0, 0);
            accB = __builtin_amdgcn_mfma_f32_32x32x16_bf16(vf1, pf[ks2], accB, 0, 0, 0);
        }
        __builtin_amdgcn_s_setprio(0);
    }

    // epilogue: lane-local 1/l; lane writes its q-row: d = 8g + 4hh + j (+32)
    float inv = 1.0f / lrow;
    size_t rowoff = (size_t)(b * 4096 + gq) * 768 + h * 64;
#pragma unroll
    for (int g = 0; g < 4; g++) {
        ushort4 o;
        o.x = f2bf(accA[4 * g + 0] * inv);
        o.y = f2bf(accA[4 * g + 1] * inv);
        o.z = f2bf(accA[4 * g + 2] * inv);
        o.w = f2bf(accA[4 * g + 3] * inv);
        *(ushort4*)(outp + rowoff + g * 8 + hh * 4) = o;
        o.x = f2bf(accB[4 * g + 0] * inv);
        o.y = f2bf(accB[4 * g + 1] * inv);
        o.z = f2bf(accB[4 * g + 2] * inv);
        o.w = f2bf(accB[4 * g + 3] * inv);
        *(ushort4*)(outp + rowoff + 32 + g * 8 + hh * 4) = o;
    }
}

// ---------------- launch ----------------
extern "C" void kernel_launch(void* const* d_in, const int* in_sizes, int n_in,
                              void* d_out, int out_size, void* d_ws, size_t ws_size,
                              hipStream_t stream) {
    const float* x      = (const float*)d_in[0];
    const float* qkv_w  = (const float*)d_in[1];
    const float* qkv_b  = (const float*)d_in[2];
    const float* proj_w = (const float*)d_in[3];
    const float* proj_b = (const float*)d_in[4];
    float* out = (float*)d_out;

    char* ws = (char*)d_ws;
    unsigned short* x_bf    = (unsigned short*)(ws);              // 12,582,912 B
    unsigned short* w1_bf   = (unsigned short*)(ws + 12582912);   //  3,538,944 B
    unsigned short* w2_bf   = (unsigned short*)(ws + 16121856);   //  1,179,648 B
    unsigned short* qkv_sep = (unsigned short*)(ws + 17301504);   // 37,748,736 B
    unsigned short* att     = (unsigned short*)(ws + 55050240);   // 12,582,912 B

    cvt_f32_to_bf16<<<2048, 256, 0, stream>>>(x,      x_bf,  6291456 / 4);
    cvt_f32_to_bf16<<<1024, 256, 0, stream>>>(qkv_w,  w1_bf, 1769472 / 4);
    cvt_f32_to_bf16<<<576,  256, 0, stream>>>(proj_w, w2_bf,  589824 / 4);

    gemm_bt<0><<<dim3(18, 64), 256, 0, stream>>>(x_bf, w1_bf, qkv_b, qkv_sep,
                                                 8192, 2304, 768);

    attn_fwd<<<dim3(32, 24), 256, 0, stream>>>(qkv_sep, att);

    gemm_bt<1><<<dim3(6, 64), 256, 0, stream>>>(att, w2_bf, proj_b, out,
                                                8192, 768, 768);
}